// Round 4
// baseline (1797.727 us; speedup 1.0000x reference)
//
#include <hip/hip_runtime.h>
#include <hip/hip_bf16.h>
#include <cstdint>

#define HID 128

// ---------------------------------------------------------------------------
// Encoder GEMM: [N,768] @ [768,32] for des (y=0) and tweet (y=1).
// Block: 256 threads -> 256 nodes x 32 cols. K-chunk 32.
// Reg-prefetch double buffering: chunk k+1 global loads issued during
// compute of chunk k (latency hidden under ~3k cyc of FMA).
// At XOR-swizzled (verified conflict-free in R3).
// ---------------------------------------------------------------------------
#define ENC_BN 256
#define ENC_KC 32

__global__ __launch_bounds__(256, 4) void enc_gemm_kernel(
    const float* __restrict__ des, const float* __restrict__ tweet,
    const float* __restrict__ Wd, const float* __restrict__ bd,
    const float* __restrict__ Wt, const float* __restrict__ bt,
    float* __restrict__ x0, int N)
{
    __shared__ float At[ENC_KC][ENC_BN];   // XOR-swizzled cols
    __shared__ float Wl[ENC_KC][32];
    const int mat = blockIdx.y;
    const float* __restrict__ X = mat ? tweet : des;
    const float* __restrict__ W = mat ? Wt : Wd;
    const float* __restrict__ B = mat ? bt : bd;
    const int n0 = blockIdx.x * ENC_BN;
    const int t = threadIdx.x;
    const int cg = t & 7;     // 4 cols each
    const int ng = t >> 3;    // 8 nodes each (0..31)

    float acc[8][4] = {};

    const int f4 = t & 7;
    const int rbase = t >> 3;
    const int sw = 4 * f4;

    float4 preA[8];
    float4 preW;

    // prologue: prefetch chunk 0
    #pragma unroll
    for (int i = 0; i < 8; ++i) {
        int node = n0 + rbase + 32 * i;
        preA[i] = make_float4(0.f, 0.f, 0.f, 0.f);
        if (node < N)
            preA[i] = *reinterpret_cast<const float4*>(X + (size_t)node * 768 + f4 * 4);
    }
    preW = *reinterpret_cast<const float4*>(W + (size_t)(t >> 3) * 32 + (t & 7) * 4);

    for (int k0 = 0; k0 < 768; k0 += ENC_KC) {
        // commit staged regs to LDS
        #pragma unroll
        for (int i = 0; i < 8; ++i) {
            int row = rbase + 32 * i;
            int colw = row ^ sw;
            At[f4 * 4 + 0][colw] = preA[i].x;
            At[f4 * 4 + 1][colw] = preA[i].y;
            At[f4 * 4 + 2][colw] = preA[i].z;
            At[f4 * 4 + 3][colw] = preA[i].w;
        }
        *reinterpret_cast<float4*>(&Wl[t >> 3][(t & 7) * 4]) = preW;
        __syncthreads();

        // prefetch chunk k0+KC (latency hidden under compute below)
        int k1 = k0 + ENC_KC;
        if (k1 < 768) {
            #pragma unroll
            for (int i = 0; i < 8; ++i) {
                int node = n0 + rbase + 32 * i;
                preA[i] = make_float4(0.f, 0.f, 0.f, 0.f);
                if (node < N)
                    preA[i] = *reinterpret_cast<const float4*>(X + (size_t)node * 768 + k1 + f4 * 4);
            }
            preW = *reinterpret_cast<const float4*>(W + (size_t)(k1 + (t >> 3)) * 32 + (t & 7) * 4);
        }

        #pragma unroll
        for (int k = 0; k < ENC_KC; ++k) {
            int fk = 4 * ((k >> 2) & 7);
            int c0 = (ng * 8) ^ fk;
            float4 a0 = *reinterpret_cast<const float4*>(&At[k][c0]);
            float4 a1 = *reinterpret_cast<const float4*>(&At[k][c0 ^ 4]);
            float4 w  = *reinterpret_cast<const float4*>(&Wl[k][cg * 4]);
            float a[8] = {a0.x, a0.y, a0.z, a0.w, a1.x, a1.y, a1.z, a1.w};
            float wc[4] = {w.x, w.y, w.z, w.w};
            #pragma unroll
            for (int j = 0; j < 8; ++j)
                #pragma unroll
                for (int c = 0; c < 4; ++c)
                    acc[j][c] = fmaf(a[j], wc[c], acc[j][c]);
        }
        __syncthreads();
    }

    float4 bb = *reinterpret_cast<const float4*>(B + cg * 4);
    float bc[4] = {bb.x, bb.y, bb.z, bb.w};
    #pragma unroll
    for (int j = 0; j < 8; ++j) {
        int node = n0 + ng * 8 + j;
        if (node >= N) break;
        float4 o;
        float v0 = acc[j][0] + bc[0]; o.x = v0 > 0.f ? v0 : 0.01f * v0;
        float v1 = acc[j][1] + bc[1]; o.y = v1 > 0.f ? v1 : 0.01f * v1;
        float v2 = acc[j][2] + bc[2]; o.z = v2 > 0.f ? v2 : 0.01f * v2;
        float v3 = acc[j][3] + bc[3]; o.w = v3 > 0.f ? v3 : 0.01f * v3;
        *reinterpret_cast<float4*>(x0 + (size_t)node * HID + mat * 32 + cg * 4) = o;
    }
}

// x0[:,64:96] = lrelu(num @ W_num + b), x0[:,96:128] = lrelu(cat @ W_cat + b)
__global__ void enc_nc_kernel(const float* __restrict__ num, const float* __restrict__ cat,
                              const float* __restrict__ Wn, const float* __restrict__ bn,
                              const float* __restrict__ Wc, const float* __restrict__ bc,
                              float* __restrict__ x0, int N)
{
    int tid = blockIdx.x * blockDim.x + threadIdx.x;
    int col = tid & 63;
    int node = tid >> 6;
    if (node >= N) return;
    float a;
    if (col < 32) {
        const float* r = num + (size_t)node * 5;
        float acc = bn[col];
        #pragma unroll
        for (int k = 0; k < 5; ++k) acc = fmaf(r[k], Wn[k * 32 + col], acc);
        a = acc;
    } else {
        int c = col & 31;
        a = fmaf(cat[node], Wc[c], bc[c]);
    }
    a = a > 0.f ? a : 0.01f * a;
    x0[(size_t)node * HID + 64 + col] = a;
}

// ---------------------------------------------------------------------------
// Dense [N,128] @ [128,128]. Block: 256 threads -> 128 nodes x 128 cols.
// Reg-prefetch double buffering for both A and W chunks.
// ---------------------------------------------------------------------------
template<bool BIAS, bool LRELU, bool DINV>
__global__ __launch_bounds__(256, 4) void gemm128_kernel(
    const float* __restrict__ in, const float* __restrict__ W,
    const float* __restrict__ b, const float* __restrict__ dinv,
    float* __restrict__ out, int N)
{
    __shared__ float At[32][128];   // XOR-swizzled cols
    __shared__ float Wl[32][128];
    const int n0 = blockIdx.x * 128;
    const int t = threadIdx.x;
    const int cg = t & 15;
    const int ng = t >> 4;

    float acc[8][8] = {};

    const int f4 = t & 7;
    const int rbase = t >> 3;   // 0..31
    const int sw = 4 * f4;
    const int wf = t & 31;
    const int kk = t >> 5;      // 0..7

    float4 preA[4], preW[4];
    #pragma unroll
    for (int i = 0; i < 4; ++i) {
        int node = n0 + rbase + 32 * i;
        preA[i] = make_float4(0.f, 0.f, 0.f, 0.f);
        if (node < N)
            preA[i] = *reinterpret_cast<const float4*>(in + (size_t)node * HID + f4 * 4);
        preW[i] = *reinterpret_cast<const float4*>(W + (size_t)(kk + 8 * i) * HID + wf * 4);
    }

    for (int k0 = 0; k0 < 128; k0 += 32) {
        #pragma unroll
        for (int i = 0; i < 4; ++i) {
            int row = rbase + 32 * i;
            int colw = row ^ sw;
            At[f4 * 4 + 0][colw] = preA[i].x;
            At[f4 * 4 + 1][colw] = preA[i].y;
            At[f4 * 4 + 2][colw] = preA[i].z;
            At[f4 * 4 + 3][colw] = preA[i].w;
            *reinterpret_cast<float4*>(&Wl[kk + 8 * i][wf * 4]) = preW[i];
        }
        __syncthreads();

        int k1 = k0 + 32;
        if (k1 < 128) {
            #pragma unroll
            for (int i = 0; i < 4; ++i) {
                int node = n0 + rbase + 32 * i;
                preA[i] = make_float4(0.f, 0.f, 0.f, 0.f);
                if (node < N)
                    preA[i] = *reinterpret_cast<const float4*>(in + (size_t)node * HID + k1 + f4 * 4);
                preW[i] = *reinterpret_cast<const float4*>(W + (size_t)(k1 + kk + 8 * i) * HID + wf * 4);
            }
        }

        #pragma unroll
        for (int k = 0; k < 32; ++k) {
            int fk = 4 * ((k >> 2) & 7);
            int c0 = (ng * 8) ^ fk;
            float4 a0 = *reinterpret_cast<const float4*>(&At[k][c0]);
            float4 a1 = *reinterpret_cast<const float4*>(&At[k][c0 ^ 4]);
            float4 w0 = *reinterpret_cast<const float4*>(&Wl[k][cg * 4]);
            float4 w1 = *reinterpret_cast<const float4*>(&Wl[k][64 + cg * 4]);
            float a[8] = {a0.x, a0.y, a0.z, a0.w, a1.x, a1.y, a1.z, a1.w};
            float wc[8] = {w0.x, w0.y, w0.z, w0.w, w1.x, w1.y, w1.z, w1.w};
            #pragma unroll
            for (int j = 0; j < 8; ++j)
                #pragma unroll
                for (int c = 0; c < 8; ++c)
                    acc[j][c] = fmaf(a[j], wc[c], acc[j][c]);
        }
        __syncthreads();
    }

    float bc[8];
    if (BIAS) {
        float4 b0 = *reinterpret_cast<const float4*>(b + cg * 4);
        float4 b1 = *reinterpret_cast<const float4*>(b + 64 + cg * 4);
        bc[0]=b0.x; bc[1]=b0.y; bc[2]=b0.z; bc[3]=b0.w;
        bc[4]=b1.x; bc[5]=b1.y; bc[6]=b1.z; bc[7]=b1.w;
    }
    #pragma unroll
    for (int j = 0; j < 8; ++j) {
        int node = n0 + ng * 8 + j;
        if (node >= N) break;
        float di;
        if (DINV) di = dinv[node];
        float o[8];
        #pragma unroll
        for (int c = 0; c < 8; ++c) {
            float a = acc[j][c];
            if (BIAS)  a += bc[c];
            if (LRELU) a = a > 0.f ? a : 0.01f * a;
            if (DINV)  a *= di;
            o[c] = a;
        }
        float4 s0 = make_float4(o[0], o[1], o[2], o[3]);
        float4 s1 = make_float4(o[4], o[5], o[6], o[7]);
        *reinterpret_cast<float4*>(out + (size_t)node * HID + cg * 4)      = s0;
        *reinterpret_cast<float4*>(out + (size_t)node * HID + 64 + cg * 4) = s1;
    }
}

// ---------------------------------------------------------------------------
// CSR build: histogram -> exclusive scan -> range-partitioned scatter
// ---------------------------------------------------------------------------
__global__ void hist_kernel(const int* __restrict__ dst, int* __restrict__ cnt, int E)
{
    int i = blockIdx.x * blockDim.x + threadIdx.x;
    int stride = gridDim.x * blockDim.x;
    for (; i < E; i += stride) atomicAdd(&cnt[dst[i]], 1);
}

__global__ void scan_block_kernel(const int* __restrict__ cnt, int* __restrict__ excl_out,
                                  int* __restrict__ part, int N)
{
    __shared__ int s[256];
    int t = threadIdx.x;
    int i = blockIdx.x * 256 + t;
    int v = (i < N) ? cnt[i] : 0;
    s[t] = v;
    __syncthreads();
    #pragma unroll
    for (int off = 1; off < 256; off <<= 1) {
        int x = (t >= off) ? s[t - off] : 0;
        __syncthreads();
        s[t] += x;
        __syncthreads();
    }
    int incl = s[t];
    if (i < N) excl_out[i] = incl - v;
    if (t == 255) part[blockIdx.x] = incl;
}

__global__ void scan_part_kernel(int* __restrict__ part, int B)
{
    __shared__ int s[512];
    int t = threadIdx.x;
    int v = (t < B) ? part[t] : 0;
    s[t] = v;
    __syncthreads();
    #pragma unroll
    for (int off = 1; off < 512; off <<= 1) {
        int x = (t >= off) ? s[t - off] : 0;
        __syncthreads();
        s[t] += x;
        __syncthreads();
    }
    int incl = s[t];
    if (t < B) part[t] = incl - v;
    if (t == B - 1) part[B] = incl;
}

__global__ void scan_final_kernel(int* __restrict__ row_ptr, const int* __restrict__ part,
                                  int* __restrict__ cursor, const int* __restrict__ cnt,
                                  float* __restrict__ dinv, int N, int B)
{
    int i = blockIdx.x * blockDim.x + threadIdx.x;
    if (i < N) {
        int rp = row_ptr[i] + part[i >> 8];
        row_ptr[i] = rp;
        cursor[i] = rp;
        dinv[i] = rsqrtf((float)(cnt[i] + 1));
    } else if (i == N) {
        row_ptr[N] = part[B];
    }
}

__global__ void scatter_kernel(const int* __restrict__ src, const int* __restrict__ dst,
                               int* __restrict__ cursor, int* __restrict__ col_idx,
                               int E, int lo, int hi)
{
    int i = blockIdx.x * blockDim.x + threadIdx.x;
    int stride = gridDim.x * blockDim.x;
    for (; i < E; i += stride) {
        int d = dst[i];
        if (d >= lo && d < hi) {
            int pos = atomicAdd(&cursor[d], 1);
            col_idx[pos] = src[i];
        }
    }
}

// ---------------------------------------------------------------------------
// GCN gather: out[i] = dinv[i] * (hs[i] + sum_{e: dst=i} hs[src_e]) + b
// ---------------------------------------------------------------------------
__global__ void conv_gather_kernel(const float* __restrict__ hs, const int* __restrict__ row_ptr,
                                   const int* __restrict__ col_idx, const float* __restrict__ dinv,
                                   const float* __restrict__ b, float* __restrict__ out, int N)
{
    int tid = blockIdx.x * blockDim.x + threadIdx.x;
    int node = tid >> 5;
    int f4 = tid & 31;
    if (node >= N) return;
    const float4* base = reinterpret_cast<const float4*>(hs);
    float4 acc = base[(size_t)node * 32 + f4];  // self-loop term
    int e = row_ptr[node], end = row_ptr[node + 1];
    while (e < end) {
        int m = end - e;
        if (m >= 32) {
            int idx = col_idx[e + f4];
            #pragma unroll 16
            for (int j = 0; j < 32; ++j) {
                int s = __shfl(idx, j, 32);
                float4 v = base[(size_t)s * 32 + f4];
                acc.x += v.x; acc.y += v.y; acc.z += v.z; acc.w += v.w;
            }
            e += 32;
        } else {
            int idx = (f4 < m) ? col_idx[e + f4] : 0;
            for (int j = 0; j < m; ++j) {
                int s = __shfl(idx, j, 32);
                float4 v = base[(size_t)s * 32 + f4];
                acc.x += v.x; acc.y += v.y; acc.z += v.z; acc.w += v.w;
            }
            e = end;
        }
    }
    float di = dinv[node];
    float4 b4 = reinterpret_cast<const float4*>(b)[f4];
    float4 o;
    o.x = fmaf(di, acc.x, b4.x);
    o.y = fmaf(di, acc.y, b4.y);
    o.z = fmaf(di, acc.z, b4.z);
    o.w = fmaf(di, acc.w, b4.w);
    reinterpret_cast<float4*>(out)[(size_t)node * 32 + f4] = o;
}

// ---------------------------------------------------------------------------
// Final: out[n,0:2] = y[n] @ W_o2 + b_o2. One wave per node.
// ---------------------------------------------------------------------------
__global__ void out_kernel(const float* __restrict__ y, const float* __restrict__ W,
                           const float* __restrict__ b, float* __restrict__ out, int N)
{
    int tid = blockIdx.x * blockDim.x + threadIdx.x;
    int lane = tid & 63;
    int node = tid >> 6;
    if (node >= N) return;
    const float* r = y + (size_t)node * HID;
    float v0 = r[lane], v1 = r[lane + 64];
    float p0 = v0 * W[lane * 2 + 0] + v1 * W[(lane + 64) * 2 + 0];
    float p1 = v0 * W[lane * 2 + 1] + v1 * W[(lane + 64) * 2 + 1];
    #pragma unroll
    for (int off = 32; off; off >>= 1) {
        p0 += __shfl_down(p0, off);
        p1 += __shfl_down(p1, off);
    }
    if (lane == 0) {
        out[(size_t)node * 2 + 0] = p0 + b[0];
        out[(size_t)node * 2 + 1] = p1 + b[1];
    }
}

extern "C" void kernel_launch(void* const* d_in, const int* in_sizes, int n_in,
                              void* d_out, int out_size, void* d_ws, size_t ws_size,
                              hipStream_t stream)
{
    const float* des   = (const float*)d_in[0];
    const float* tweet = (const float*)d_in[1];
    const float* num   = (const float*)d_in[2];
    const float* cat   = (const float*)d_in[3];
    const int*   eidx  = (const int*)d_in[4];
    const float* W_des = (const float*)d_in[5];  const float* b_des = (const float*)d_in[6];
    const float* W_tw  = (const float*)d_in[7];  const float* b_tw  = (const float*)d_in[8];
    const float* W_num = (const float*)d_in[9];  const float* b_num = (const float*)d_in[10];
    const float* W_cat = (const float*)d_in[11]; const float* b_cat = (const float*)d_in[12];
    const float* W_in  = (const float*)d_in[13]; const float* b_in  = (const float*)d_in[14];
    const float* W_g1  = (const float*)d_in[15]; const float* b_g1  = (const float*)d_in[16];
    const float* W_g2  = (const float*)d_in[17]; const float* b_g2  = (const float*)d_in[18];
    const float* W_o1  = (const float*)d_in[19]; const float* b_o1  = (const float*)d_in[20];
    const float* W_o2  = (const float*)d_in[21]; const float* b_o2  = (const float*)d_in[22];
    float* out = (float*)d_out;

    const int N = in_sizes[0] / 768;
    const int E = in_sizes[4] / 2;
    const int* src = eidx;
    const int* dst = eidx + E;

    // workspace layout
    char* ws = (char*)d_ws;
    const size_t szF = (size_t)N * HID * sizeof(float);
    float* F0 = (float*)ws;                    ws += szF;
    float* F1 = (float*)ws;                    ws += szF;
    float* F2 = (float*)ws;                    ws += szF;
    int* cnt      = (int*)ws;                  ws += ((size_t)N * 4 + 255) & ~255ULL;
    int* row_ptr  = (int*)ws;                  ws += (((size_t)N + 1) * 4 + 255) & ~255ULL;
    int* cursor   = (int*)ws;                  ws += ((size_t)N * 4 + 255) & ~255ULL;
    int* part     = (int*)ws;                  ws += 4096;
    float* dinv   = (float*)ws;                ws += ((size_t)N * 4 + 255) & ~255ULL;
    int* col_idx  = (int*)ws;                  ws += (size_t)E * 4;

    const int B = (N + 255) / 256;  // scan blocks (<= 512)

    // ---- CSR build ----
    hipMemsetAsync(cnt, 0, (size_t)N * sizeof(int), stream);
    hist_kernel<<<1024, 256, 0, stream>>>(dst, cnt, E);
    scan_block_kernel<<<B, 256, 0, stream>>>(cnt, row_ptr, part, N);
    scan_part_kernel<<<1, 512, 0, stream>>>(part, B);
    scan_final_kernel<<<(N + 256) / 256 + 1, 256, 0, stream>>>(row_ptr, part, cursor, cnt, dinv, N, B);
    {
        const int NPART = 4;
        int step = (N + NPART - 1) / NPART;
        for (int p = 0; p < NPART; ++p) {
            int lo = p * step;
            int hi = (lo + step < N) ? lo + step : N;
            scatter_kernel<<<1024, 256, 0, stream>>>(src, dst, cursor, col_idx, E, lo, hi);
        }
    }

    // ---- encoder -> F0 ----
    {
        dim3 grid((N + ENC_BN - 1) / ENC_BN, 2);
        enc_gemm_kernel<<<grid, 256, 0, stream>>>(des, tweet, W_des, b_des, W_tw, b_tw, F0, N);
        enc_nc_kernel<<<((size_t)N * 64 + 255) / 256, 256, 0, stream>>>(num, cat, W_num, b_num, W_cat, b_cat, F0, N);
    }

    int ggrid = (N + 127) / 128;

    // ---- x1 = lrelu(x0 @ W_in + b_in) -> F1 ----
    gemm128_kernel<true, true, false><<<ggrid, 256, 0, stream>>>(F0, W_in, b_in, nullptr, F1, N);

    // ---- conv1: hs1 = (x1 @ W_g1) * dinv -> F2 ; c1 -> F0 ----
    gemm128_kernel<false, false, true><<<ggrid, 256, 0, stream>>>(F1, W_g1, nullptr, dinv, F2, N);
    conv_gather_kernel<<<((size_t)N * 32 + 255) / 256, 256, 0, stream>>>(F2, row_ptr, col_idx, dinv, b_g1, F0, N);

    // ---- conv2: hs2 = (c1 @ W_g2) * dinv -> F1 ; c2 -> F2 ----
    gemm128_kernel<false, false, true><<<ggrid, 256, 0, stream>>>(F0, W_g2, nullptr, dinv, F1, N);
    conv_gather_kernel<<<((size_t)N * 32 + 255) / 256, 256, 0, stream>>>(F1, row_ptr, col_idx, dinv, b_g2, F2, N);

    // ---- y = lrelu(c2 @ W_o1 + b_o1) -> F0 ----
    gemm128_kernel<true, true, false><<<ggrid, 256, 0, stream>>>(F2, W_o1, b_o1, nullptr, F0, N);

    // ---- out = y @ W_o2 + b_o2 ----
    out_kernel<<<((size_t)N * 64 + 255) / 256, 256, 0, stream>>>(F0, W_o2, b_o2, out, N);
}

// Round 5
// 1255.273 us; speedup vs baseline: 1.4321x; 1.4321x over previous
//
#include <hip/hip_runtime.h>
#include <hip/hip_bf16.h>
#include <cstdint>

#define HID 128

// ---------------------------------------------------------------------------
// Encoder GEMM: [N,768] @ [768,32] for des (y=0) and tweet (y=1).
// Block: 512 threads -> 256 nodes x 32 cols. K-chunk 32.
// Thread: 4 nodes x 4 cols (cg = t&7, ng = t>>3). No reg prefetch (R4 spilled);
// latency hidden by occupancy: 8 waves/block, ~3 blocks/CU.
// At XOR-swizzled (verified conflict-free in R3).
// ---------------------------------------------------------------------------
#define ENC_BN 256
#define ENC_KC 32

__global__ __launch_bounds__(512, 4) void enc_gemm_kernel(
    const float* __restrict__ des, const float* __restrict__ tweet,
    const float* __restrict__ Wd, const float* __restrict__ bd,
    const float* __restrict__ Wt, const float* __restrict__ bt,
    float* __restrict__ x0, int N)
{
    __shared__ float At[ENC_KC][ENC_BN];   // XOR-swizzled cols
    __shared__ float Wl[ENC_KC][32];
    const int mat = blockIdx.y;
    const float* __restrict__ X = mat ? tweet : des;
    const float* __restrict__ W = mat ? Wt : Wd;
    const float* __restrict__ B = mat ? bt : bd;
    const int n0 = blockIdx.x * ENC_BN;
    const int t = threadIdx.x;          // 0..511
    const int cg = t & 7;               // 4 cols each
    const int ng = t >> 3;              // 0..63, 4 nodes each

    float acc[4][4] = {};

    const int f4 = t & 7;
    const int rbase = t >> 3;           // 0..63
    const int sw = 4 * f4;

    for (int k0 = 0; k0 < 768; k0 += ENC_KC) {
        // stage A: 256 rows x 32 k, transposed+swizzled; 4 rows/thread
        #pragma unroll
        for (int i = 0; i < 4; ++i) {
            int row = rbase + 64 * i;
            int node = n0 + row;
            float4 v = make_float4(0.f, 0.f, 0.f, 0.f);
            if (node < N)
                v = *reinterpret_cast<const float4*>(X + (size_t)node * 768 + k0 + f4 * 4);
            int colw = row ^ sw;
            At[f4 * 4 + 0][colw] = v.x;
            At[f4 * 4 + 1][colw] = v.y;
            At[f4 * 4 + 2][colw] = v.z;
            At[f4 * 4 + 3][colw] = v.w;
        }
        // stage W: 32x32 -> first 4 waves only (wave-uniform branch)
        if (t < 256) {
            float4 wv = *reinterpret_cast<const float4*>(W + (size_t)(k0 + (t >> 3)) * 32 + (t & 7) * 4);
            *reinterpret_cast<float4*>(&Wl[t >> 3][(t & 7) * 4]) = wv;
        }
        __syncthreads();
        #pragma unroll
        for (int k = 0; k < ENC_KC; ++k) {
            int fk = 4 * ((k >> 2) & 7);
            int c0 = (ng * 4) ^ fk;
            float4 a = *reinterpret_cast<const float4*>(&At[k][c0]);     // 4 nodes
            float4 w = *reinterpret_cast<const float4*>(&Wl[k][cg * 4]); // 4 cols
            float av[4] = {a.x, a.y, a.z, a.w};
            float wc[4] = {w.x, w.y, w.z, w.w};
            #pragma unroll
            for (int j = 0; j < 4; ++j)
                #pragma unroll
                for (int c = 0; c < 4; ++c)
                    acc[j][c] = fmaf(av[j], wc[c], acc[j][c]);
        }
        __syncthreads();
    }

    float4 bb = *reinterpret_cast<const float4*>(B + cg * 4);
    float bc[4] = {bb.x, bb.y, bb.z, bb.w};
    #pragma unroll
    for (int j = 0; j < 4; ++j) {
        int node = n0 + ng * 4 + j;
        if (node >= N) break;
        float4 o;
        float v0 = acc[j][0] + bc[0]; o.x = v0 > 0.f ? v0 : 0.01f * v0;
        float v1 = acc[j][1] + bc[1]; o.y = v1 > 0.f ? v1 : 0.01f * v1;
        float v2 = acc[j][2] + bc[2]; o.z = v2 > 0.f ? v2 : 0.01f * v2;
        float v3 = acc[j][3] + bc[3]; o.w = v3 > 0.f ? v3 : 0.01f * v3;
        *reinterpret_cast<float4*>(x0 + (size_t)node * HID + mat * 32 + cg * 4) = o;
    }
}

// x0[:,64:96] = lrelu(num @ W_num + b), x0[:,96:128] = lrelu(cat @ W_cat + b)
__global__ void enc_nc_kernel(const float* __restrict__ num, const float* __restrict__ cat,
                              const float* __restrict__ Wn, const float* __restrict__ bn,
                              const float* __restrict__ Wc, const float* __restrict__ bc,
                              float* __restrict__ x0, int N)
{
    int tid = blockIdx.x * blockDim.x + threadIdx.x;
    int col = tid & 63;
    int node = tid >> 6;
    if (node >= N) return;
    float a;
    if (col < 32) {
        const float* r = num + (size_t)node * 5;
        float acc = bn[col];
        #pragma unroll
        for (int k = 0; k < 5; ++k) acc = fmaf(r[k], Wn[k * 32 + col], acc);
        a = acc;
    } else {
        int c = col & 31;
        a = fmaf(cat[node], Wc[c], bc[c]);
    }
    a = a > 0.f ? a : 0.01f * a;
    x0[(size_t)node * HID + 64 + col] = a;
}

// ---------------------------------------------------------------------------
// Dense [N,128] @ [128,128]. Block: 512 threads -> 128 nodes x 128 cols.
// Thread: 4 nodes x (4+4) cols (cg = t&15, ng = t>>4). K-chunk 32.
// ---------------------------------------------------------------------------
template<bool BIAS, bool LRELU, bool DINV>
__global__ __launch_bounds__(512, 4) void gemm128_kernel(
    const float* __restrict__ in, const float* __restrict__ W,
    const float* __restrict__ b, const float* __restrict__ dinv,
    float* __restrict__ out, int N)
{
    __shared__ float At[32][128];   // XOR-swizzled cols
    __shared__ float Wl[32][128];
    const int n0 = blockIdx.x * 128;
    const int t = threadIdx.x;      // 0..511
    const int cg = t & 15;          // cols {cg*4, 64+cg*4}
    const int ng = t >> 4;          // 0..31, 4 nodes each

    float acc[4][8] = {};

    const int f4 = t & 7;
    const int rbase = t >> 3;       // 0..63
    const int sw = 4 * f4;
    const int wf = t & 31;
    const int kk = t >> 5;          // 0..15

    for (int k0 = 0; k0 < 128; k0 += 32) {
        // stage A: 128 rows x 32 k; 2 rows/thread
        #pragma unroll
        for (int i = 0; i < 2; ++i) {
            int row = rbase + 64 * i;
            int node = n0 + row;
            float4 v = make_float4(0.f, 0.f, 0.f, 0.f);
            if (node < N)
                v = *reinterpret_cast<const float4*>(in + (size_t)node * HID + k0 + f4 * 4);
            int colw = row ^ sw;
            At[f4 * 4 + 0][colw] = v.x;
            At[f4 * 4 + 1][colw] = v.y;
            At[f4 * 4 + 2][colw] = v.z;
            At[f4 * 4 + 3][colw] = v.w;
        }
        // stage W: 32 k x 128 c; 2 float4/thread
        #pragma unroll
        for (int i = 0; i < 2; ++i) {
            int k = kk + 16 * i;
            float4 wv = *reinterpret_cast<const float4*>(W + (size_t)(k0 + k) * HID + wf * 4);
            *reinterpret_cast<float4*>(&Wl[k][wf * 4]) = wv;
        }
        __syncthreads();
        #pragma unroll
        for (int k = 0; k < 32; ++k) {
            int fk = 4 * ((k >> 2) & 7);
            int c0 = (ng * 4) ^ fk;
            float4 a  = *reinterpret_cast<const float4*>(&At[k][c0]);
            float4 w0 = *reinterpret_cast<const float4*>(&Wl[k][cg * 4]);
            float4 w1 = *reinterpret_cast<const float4*>(&Wl[k][64 + cg * 4]);
            float av[4] = {a.x, a.y, a.z, a.w};
            float wc[8] = {w0.x, w0.y, w0.z, w0.w, w1.x, w1.y, w1.z, w1.w};
            #pragma unroll
            for (int j = 0; j < 4; ++j)
                #pragma unroll
                for (int c = 0; c < 8; ++c)
                    acc[j][c] = fmaf(av[j], wc[c], acc[j][c]);
        }
        __syncthreads();
    }

    float bc[8];
    if (BIAS) {
        float4 b0 = *reinterpret_cast<const float4*>(b + cg * 4);
        float4 b1 = *reinterpret_cast<const float4*>(b + 64 + cg * 4);
        bc[0]=b0.x; bc[1]=b0.y; bc[2]=b0.z; bc[3]=b0.w;
        bc[4]=b1.x; bc[5]=b1.y; bc[6]=b1.z; bc[7]=b1.w;
    }
    #pragma unroll
    for (int j = 0; j < 4; ++j) {
        int node = n0 + ng * 4 + j;
        if (node >= N) break;
        float di;
        if (DINV) di = dinv[node];
        float o[8];
        #pragma unroll
        for (int c = 0; c < 8; ++c) {
            float a = acc[j][c];
            if (BIAS)  a += bc[c];
            if (LRELU) a = a > 0.f ? a : 0.01f * a;
            if (DINV)  a *= di;
            o[c] = a;
        }
        float4 s0 = make_float4(o[0], o[1], o[2], o[3]);
        float4 s1 = make_float4(o[4], o[5], o[6], o[7]);
        *reinterpret_cast<float4*>(out + (size_t)node * HID + cg * 4)      = s0;
        *reinterpret_cast<float4*>(out + (size_t)node * HID + 64 + cg * 4) = s1;
    }
}

// ---------------------------------------------------------------------------
// CSR build: histogram -> exclusive scan -> range-partitioned scatter
// ---------------------------------------------------------------------------
__global__ void hist_kernel(const int* __restrict__ dst, int* __restrict__ cnt, int E)
{
    int i = blockIdx.x * blockDim.x + threadIdx.x;
    int stride = gridDim.x * blockDim.x;
    for (; i < E; i += stride) atomicAdd(&cnt[dst[i]], 1);
}

__global__ void scan_block_kernel(const int* __restrict__ cnt, int* __restrict__ excl_out,
                                  int* __restrict__ part, int N)
{
    __shared__ int s[256];
    int t = threadIdx.x;
    int i = blockIdx.x * 256 + t;
    int v = (i < N) ? cnt[i] : 0;
    s[t] = v;
    __syncthreads();
    #pragma unroll
    for (int off = 1; off < 256; off <<= 1) {
        int x = (t >= off) ? s[t - off] : 0;
        __syncthreads();
        s[t] += x;
        __syncthreads();
    }
    int incl = s[t];
    if (i < N) excl_out[i] = incl - v;
    if (t == 255) part[blockIdx.x] = incl;
}

__global__ void scan_part_kernel(int* __restrict__ part, int B)
{
    __shared__ int s[512];
    int t = threadIdx.x;
    int v = (t < B) ? part[t] : 0;
    s[t] = v;
    __syncthreads();
    #pragma unroll
    for (int off = 1; off < 512; off <<= 1) {
        int x = (t >= off) ? s[t - off] : 0;
        __syncthreads();
        s[t] += x;
        __syncthreads();
    }
    int incl = s[t];
    if (t < B) part[t] = incl - v;
    if (t == B - 1) part[B] = incl;
}

__global__ void scan_final_kernel(int* __restrict__ row_ptr, const int* __restrict__ part,
                                  int* __restrict__ cursor, const int* __restrict__ cnt,
                                  float* __restrict__ dinv, int N, int B)
{
    int i = blockIdx.x * blockDim.x + threadIdx.x;
    if (i < N) {
        int rp = row_ptr[i] + part[i >> 8];
        row_ptr[i] = rp;
        cursor[i] = rp;
        dinv[i] = rsqrtf((float)(cnt[i] + 1));
    } else if (i == N) {
        row_ptr[N] = part[B];
    }
}

__global__ void scatter_kernel(const int* __restrict__ src, const int* __restrict__ dst,
                               int* __restrict__ cursor, int* __restrict__ col_idx,
                               int E, int lo, int hi)
{
    int i = blockIdx.x * blockDim.x + threadIdx.x;
    int stride = gridDim.x * blockDim.x;
    for (; i < E; i += stride) {
        int d = dst[i];
        if (d >= lo && d < hi) {
            int pos = atomicAdd(&cursor[d], 1);
            col_idx[pos] = src[i];
        }
    }
}

// ---------------------------------------------------------------------------
// GCN gather: out[i] = dinv[i] * (hs[i] + sum_{e: dst=i} hs[src_e]) + b
// ---------------------------------------------------------------------------
__global__ void conv_gather_kernel(const float* __restrict__ hs, const int* __restrict__ row_ptr,
                                   const int* __restrict__ col_idx, const float* __restrict__ dinv,
                                   const float* __restrict__ b, float* __restrict__ out, int N)
{
    int tid = blockIdx.x * blockDim.x + threadIdx.x;
    int node = tid >> 5;
    int f4 = tid & 31;
    if (node >= N) return;
    const float4* base = reinterpret_cast<const float4*>(hs);
    float4 acc = base[(size_t)node * 32 + f4];  // self-loop term
    int e = row_ptr[node], end = row_ptr[node + 1];
    while (e < end) {
        int m = end - e;
        if (m >= 32) {
            int idx = col_idx[e + f4];
            #pragma unroll 8
            for (int j = 0; j < 32; ++j) {
                int s = __shfl(idx, j, 32);
                float4 v = base[(size_t)s * 32 + f4];
                acc.x += v.x; acc.y += v.y; acc.z += v.z; acc.w += v.w;
            }
            e += 32;
        } else {
            int idx = (f4 < m) ? col_idx[e + f4] : 0;
            for (int j = 0; j < m; ++j) {
                int s = __shfl(idx, j, 32);
                float4 v = base[(size_t)s * 32 + f4];
                acc.x += v.x; acc.y += v.y; acc.z += v.z; acc.w += v.w;
            }
            e = end;
        }
    }
    float di = dinv[node];
    float4 b4 = reinterpret_cast<const float4*>(b)[f4];
    float4 o;
    o.x = fmaf(di, acc.x, b4.x);
    o.y = fmaf(di, acc.y, b4.y);
    o.z = fmaf(di, acc.z, b4.z);
    o.w = fmaf(di, acc.w, b4.w);
    reinterpret_cast<float4*>(out)[(size_t)node * 32 + f4] = o;
}

// ---------------------------------------------------------------------------
// Final: out[n,0:2] = y[n] @ W_o2 + b_o2. One wave per node.
// ---------------------------------------------------------------------------
__global__ void out_kernel(const float* __restrict__ y, const float* __restrict__ W,
                           const float* __restrict__ b, float* __restrict__ out, int N)
{
    int tid = blockIdx.x * blockDim.x + threadIdx.x;
    int lane = tid & 63;
    int node = tid >> 6;
    if (node >= N) return;
    const float* r = y + (size_t)node * HID;
    float v0 = r[lane], v1 = r[lane + 64];
    float p0 = v0 * W[lane * 2 + 0] + v1 * W[(lane + 64) * 2 + 0];
    float p1 = v0 * W[lane * 2 + 1] + v1 * W[(lane + 64) * 2 + 1];
    #pragma unroll
    for (int off = 32; off; off >>= 1) {
        p0 += __shfl_down(p0, off);
        p1 += __shfl_down(p1, off);
    }
    if (lane == 0) {
        out[(size_t)node * 2 + 0] = p0 + b[0];
        out[(size_t)node * 2 + 1] = p1 + b[1];
    }
}

extern "C" void kernel_launch(void* const* d_in, const int* in_sizes, int n_in,
                              void* d_out, int out_size, void* d_ws, size_t ws_size,
                              hipStream_t stream)
{
    const float* des   = (const float*)d_in[0];
    const float* tweet = (const float*)d_in[1];
    const float* num   = (const float*)d_in[2];
    const float* cat   = (const float*)d_in[3];
    const int*   eidx  = (const int*)d_in[4];
    const float* W_des = (const float*)d_in[5];  const float* b_des = (const float*)d_in[6];
    const float* W_tw  = (const float*)d_in[7];  const float* b_tw  = (const float*)d_in[8];
    const float* W_num = (const float*)d_in[9];  const float* b_num = (const float*)d_in[10];
    const float* W_cat = (const float*)d_in[11]; const float* b_cat = (const float*)d_in[12];
    const float* W_in  = (const float*)d_in[13]; const float* b_in  = (const float*)d_in[14];
    const float* W_g1  = (const float*)d_in[15]; const float* b_g1  = (const float*)d_in[16];
    const float* W_g2  = (const float*)d_in[17]; const float* b_g2  = (const float*)d_in[18];
    const float* W_o1  = (const float*)d_in[19]; const float* b_o1  = (const float*)d_in[20];
    const float* W_o2  = (const float*)d_in[21]; const float* b_o2  = (const float*)d_in[22];
    float* out = (float*)d_out;

    const int N = in_sizes[0] / 768;
    const int E = in_sizes[4] / 2;
    const int* src = eidx;
    const int* dst = eidx + E;

    // workspace layout
    char* ws = (char*)d_ws;
    const size_t szF = (size_t)N * HID * sizeof(float);
    float* F0 = (float*)ws;                    ws += szF;
    float* F1 = (float*)ws;                    ws += szF;
    float* F2 = (float*)ws;                    ws += szF;
    int* cnt      = (int*)ws;                  ws += ((size_t)N * 4 + 255) & ~255ULL;
    int* row_ptr  = (int*)ws;                  ws += (((size_t)N + 1) * 4 + 255) & ~255ULL;
    int* cursor   = (int*)ws;                  ws += ((size_t)N * 4 + 255) & ~255ULL;
    int* part     = (int*)ws;                  ws += 4096;
    float* dinv   = (float*)ws;                ws += ((size_t)N * 4 + 255) & ~255ULL;
    int* col_idx  = (int*)ws;                  ws += (size_t)E * 4;

    const int B = (N + 255) / 256;  // scan blocks (<= 512)

    // ---- CSR build ----
    hipMemsetAsync(cnt, 0, (size_t)N * sizeof(int), stream);
    hist_kernel<<<1024, 256, 0, stream>>>(dst, cnt, E);
    scan_block_kernel<<<B, 256, 0, stream>>>(cnt, row_ptr, part, N);
    scan_part_kernel<<<1, 512, 0, stream>>>(part, B);
    scan_final_kernel<<<(N + 256) / 256 + 1, 256, 0, stream>>>(row_ptr, part, cursor, cnt, dinv, N, B);
    {
        const int NPART = 4;
        int step = (N + NPART - 1) / NPART;
        for (int p = 0; p < NPART; ++p) {
            int lo = p * step;
            int hi = (lo + step < N) ? lo + step : N;
            scatter_kernel<<<1024, 256, 0, stream>>>(src, dst, cursor, col_idx, E, lo, hi);
        }
    }

    // ---- encoder -> F0 ----
    {
        dim3 grid((N + ENC_BN - 1) / ENC_BN, 2);
        enc_gemm_kernel<<<grid, 512, 0, stream>>>(des, tweet, W_des, b_des, W_tw, b_tw, F0, N);
        enc_nc_kernel<<<((size_t)N * 64 + 255) / 256, 256, 0, stream>>>(num, cat, W_num, b_num, W_cat, b_cat, F0, N);
    }

    int ggrid = (N + 127) / 128;

    // ---- x1 = lrelu(x0 @ W_in + b_in) -> F1 ----
    gemm128_kernel<true, true, false><<<ggrid, 512, 0, stream>>>(F0, W_in, b_in, nullptr, F1, N);

    // ---- conv1: hs1 = (x1 @ W_g1) * dinv -> F2 ; c1 -> F0 ----
    gemm128_kernel<false, false, true><<<ggrid, 512, 0, stream>>>(F1, W_g1, nullptr, dinv, F2, N);
    conv_gather_kernel<<<((size_t)N * 32 + 255) / 256, 256, 0, stream>>>(F2, row_ptr, col_idx, dinv, b_g1, F0, N);

    // ---- conv2: hs2 = (c1 @ W_g2) * dinv -> F1 ; c2 -> F2 ----
    gemm128_kernel<false, false, true><<<ggrid, 512, 0, stream>>>(F0, W_g2, nullptr, dinv, F1, N);
    conv_gather_kernel<<<((size_t)N * 32 + 255) / 256, 256, 0, stream>>>(F1, row_ptr, col_idx, dinv, b_g2, F2, N);

    // ---- y = lrelu(c2 @ W_o1 + b_o1) -> F0 ----
    gemm128_kernel<true, true, false><<<ggrid, 512, 0, stream>>>(F2, W_o1, b_o1, nullptr, F0, N);

    // ---- out = y @ W_o2 + b_o2 ----
    out_kernel<<<((size_t)N * 64 + 255) / 256, 256, 0, stream>>>(F0, W_o2, b_o2, out, N);
}

// Round 6
// 1082.229 us; speedup vs baseline: 1.6611x; 1.1599x over previous
//
#include <hip/hip_runtime.h>
#include <hip/hip_bf16.h>
#include <cstdint>

#define HID 128

__device__ __forceinline__ unsigned pack_bf16(float a, float b)
{
    __hip_bfloat16 ha = __float2bfloat16(a);
    __hip_bfloat16 hb = __float2bfloat16(b);
    unsigned short ua = *reinterpret_cast<unsigned short*>(&ha);
    unsigned short ub = *reinterpret_cast<unsigned short*>(&hb);
    return (unsigned)ua | ((unsigned)ub << 16);
}

__device__ __forceinline__ float bf16_lo(unsigned u)
{
    unsigned v = u << 16;
    return *reinterpret_cast<float*>(&v);
}
__device__ __forceinline__ float bf16_hi(unsigned u)
{
    unsigned v = u & 0xffff0000u;
    return *reinterpret_cast<float*>(&v);
}

// ---------------------------------------------------------------------------
// Encoder GEMM: [N,768] @ [768,32] for des (y=0) and tweet (y=1).
// Block: 512 threads -> 256 nodes x 32 cols. K-chunk 32.  (R5 structure)
// ---------------------------------------------------------------------------
#define ENC_BN 256
#define ENC_KC 32

__global__ __launch_bounds__(512, 4) void enc_gemm_kernel(
    const float* __restrict__ des, const float* __restrict__ tweet,
    const float* __restrict__ Wd, const float* __restrict__ bd,
    const float* __restrict__ Wt, const float* __restrict__ bt,
    float* __restrict__ x0, int N)
{
    __shared__ float At[ENC_KC][ENC_BN];   // XOR-swizzled cols
    __shared__ float Wl[ENC_KC][32];
    const int mat = blockIdx.y;
    const float* __restrict__ X = mat ? tweet : des;
    const float* __restrict__ W = mat ? Wt : Wd;
    const float* __restrict__ B = mat ? bt : bd;
    const int n0 = blockIdx.x * ENC_BN;
    const int t = threadIdx.x;          // 0..511
    const int cg = t & 7;               // 4 cols each
    const int ng = t >> 3;              // 0..63, 4 nodes each

    float acc[4][4] = {};

    const int f4 = t & 7;
    const int rbase = t >> 3;           // 0..63
    const int sw = 4 * f4;

    for (int k0 = 0; k0 < 768; k0 += ENC_KC) {
        #pragma unroll
        for (int i = 0; i < 4; ++i) {
            int row = rbase + 64 * i;
            int node = n0 + row;
            float4 v = make_float4(0.f, 0.f, 0.f, 0.f);
            if (node < N)
                v = *reinterpret_cast<const float4*>(X + (size_t)node * 768 + k0 + f4 * 4);
            int colw = row ^ sw;
            At[f4 * 4 + 0][colw] = v.x;
            At[f4 * 4 + 1][colw] = v.y;
            At[f4 * 4 + 2][colw] = v.z;
            At[f4 * 4 + 3][colw] = v.w;
        }
        if (t < 256) {
            float4 wv = *reinterpret_cast<const float4*>(W + (size_t)(k0 + (t >> 3)) * 32 + (t & 7) * 4);
            *reinterpret_cast<float4*>(&Wl[t >> 3][(t & 7) * 4]) = wv;
        }
        __syncthreads();
        #pragma unroll
        for (int k = 0; k < ENC_KC; ++k) {
            int fk = 4 * ((k >> 2) & 7);
            int c0 = (ng * 4) ^ fk;
            float4 a = *reinterpret_cast<const float4*>(&At[k][c0]);
            float4 w = *reinterpret_cast<const float4*>(&Wl[k][cg * 4]);
            float av[4] = {a.x, a.y, a.z, a.w};
            float wc[4] = {w.x, w.y, w.z, w.w};
            #pragma unroll
            for (int j = 0; j < 4; ++j)
                #pragma unroll
                for (int c = 0; c < 4; ++c)
                    acc[j][c] = fmaf(av[j], wc[c], acc[j][c]);
        }
        __syncthreads();
    }

    float4 bb = *reinterpret_cast<const float4*>(B + cg * 4);
    float bc[4] = {bb.x, bb.y, bb.z, bb.w};
    #pragma unroll
    for (int j = 0; j < 4; ++j) {
        int node = n0 + ng * 4 + j;
        if (node >= N) break;
        float4 o;
        float v0 = acc[j][0] + bc[0]; o.x = v0 > 0.f ? v0 : 0.01f * v0;
        float v1 = acc[j][1] + bc[1]; o.y = v1 > 0.f ? v1 : 0.01f * v1;
        float v2 = acc[j][2] + bc[2]; o.z = v2 > 0.f ? v2 : 0.01f * v2;
        float v3 = acc[j][3] + bc[3]; o.w = v3 > 0.f ? v3 : 0.01f * v3;
        *reinterpret_cast<float4*>(x0 + (size_t)node * HID + mat * 32 + cg * 4) = o;
    }
}

// x0[:,64:96] = lrelu(num @ W_num + b), x0[:,96:128] = lrelu(cat @ W_cat + b)
__global__ void enc_nc_kernel(const float* __restrict__ num, const float* __restrict__ cat,
                              const float* __restrict__ Wn, const float* __restrict__ bn,
                              const float* __restrict__ Wc, const float* __restrict__ bc,
                              float* __restrict__ x0, int N)
{
    int tid = blockIdx.x * blockDim.x + threadIdx.x;
    int col = tid & 63;
    int node = tid >> 6;
    if (node >= N) return;
    float a;
    if (col < 32) {
        const float* r = num + (size_t)node * 5;
        float acc = bn[col];
        #pragma unroll
        for (int k = 0; k < 5; ++k) acc = fmaf(r[k], Wn[k * 32 + col], acc);
        a = acc;
    } else {
        int c = col & 31;
        a = fmaf(cat[node], Wc[c], bc[c]);
    }
    a = a > 0.f ? a : 0.01f * a;
    x0[(size_t)node * HID + 64 + col] = a;
}

// ---------------------------------------------------------------------------
// Dense [N,128] @ [128,128]. Block: 512 threads -> 128 nodes x 128 cols.
// BF16OUT: write bf16 rows (for conv gather); else f32.
// ---------------------------------------------------------------------------
template<bool BIAS, bool LRELU, bool DINV, bool BF16OUT>
__global__ __launch_bounds__(512, 4) void gemm128_kernel(
    const float* __restrict__ in, const float* __restrict__ W,
    const float* __restrict__ b, const float* __restrict__ dinv,
    void* __restrict__ outp, int N)
{
    __shared__ float At[32][128];   // XOR-swizzled cols
    __shared__ float Wl[32][128];
    const int n0 = blockIdx.x * 128;
    const int t = threadIdx.x;      // 0..511
    const int cg = t & 15;          // cols {cg*4, 64+cg*4}
    const int ng = t >> 4;          // 0..31, 4 nodes each

    float acc[4][8] = {};

    const int f4 = t & 7;
    const int rbase = t >> 3;       // 0..63
    const int sw = 4 * f4;
    const int wf = t & 31;
    const int kk = t >> 5;          // 0..15

    for (int k0 = 0; k0 < 128; k0 += 32) {
        #pragma unroll
        for (int i = 0; i < 2; ++i) {
            int row = rbase + 64 * i;
            int node = n0 + row;
            float4 v = make_float4(0.f, 0.f, 0.f, 0.f);
            if (node < N)
                v = *reinterpret_cast<const float4*>(in + (size_t)node * HID + k0 + f4 * 4);
            int colw = row ^ sw;
            At[f4 * 4 + 0][colw] = v.x;
            At[f4 * 4 + 1][colw] = v.y;
            At[f4 * 4 + 2][colw] = v.z;
            At[f4 * 4 + 3][colw] = v.w;
        }
        #pragma unroll
        for (int i = 0; i < 2; ++i) {
            int k = kk + 16 * i;
            float4 wv = *reinterpret_cast<const float4*>(W + (size_t)(k0 + k) * HID + wf * 4);
            *reinterpret_cast<float4*>(&Wl[k][wf * 4]) = wv;
        }
        __syncthreads();
        #pragma unroll
        for (int k = 0; k < 32; ++k) {
            int fk = 4 * ((k >> 2) & 7);
            int c0 = (ng * 4) ^ fk;
            float4 a  = *reinterpret_cast<const float4*>(&At[k][c0]);
            float4 w0 = *reinterpret_cast<const float4*>(&Wl[k][cg * 4]);
            float4 w1 = *reinterpret_cast<const float4*>(&Wl[k][64 + cg * 4]);
            float av[4] = {a.x, a.y, a.z, a.w};
            float wc[8] = {w0.x, w0.y, w0.z, w0.w, w1.x, w1.y, w1.z, w1.w};
            #pragma unroll
            for (int j = 0; j < 4; ++j)
                #pragma unroll
                for (int c = 0; c < 8; ++c)
                    acc[j][c] = fmaf(av[j], wc[c], acc[j][c]);
        }
        __syncthreads();
    }

    float bc[8];
    if (BIAS) {
        float4 b0 = *reinterpret_cast<const float4*>(b + cg * 4);
        float4 b1 = *reinterpret_cast<const float4*>(b + 64 + cg * 4);
        bc[0]=b0.x; bc[1]=b0.y; bc[2]=b0.z; bc[3]=b0.w;
        bc[4]=b1.x; bc[5]=b1.y; bc[6]=b1.z; bc[7]=b1.w;
    }
    #pragma unroll
    for (int j = 0; j < 4; ++j) {
        int node = n0 + ng * 4 + j;
        if (node >= N) break;
        float di;
        if (DINV) di = dinv[node];
        float o[8];
        #pragma unroll
        for (int c = 0; c < 8; ++c) {
            float a = acc[j][c];
            if (BIAS)  a += bc[c];
            if (LRELU) a = a > 0.f ? a : 0.01f * a;
            if (DINV)  a *= di;
            o[c] = a;
        }
        if (BF16OUT) {
            unsigned* row = reinterpret_cast<unsigned*>(outp) + (size_t)node * (HID / 2);
            uint2 s0 = make_uint2(pack_bf16(o[0], o[1]), pack_bf16(o[2], o[3]));
            uint2 s1 = make_uint2(pack_bf16(o[4], o[5]), pack_bf16(o[6], o[7]));
            *reinterpret_cast<uint2*>(row + cg * 2)      = s0;
            *reinterpret_cast<uint2*>(row + 32 + cg * 2) = s1;
        } else {
            float* out = reinterpret_cast<float*>(outp);
            float4 s0 = make_float4(o[0], o[1], o[2], o[3]);
            float4 s1 = make_float4(o[4], o[5], o[6], o[7]);
            *reinterpret_cast<float4*>(out + (size_t)node * HID + cg * 4)      = s0;
            *reinterpret_cast<float4*>(out + (size_t)node * HID + 64 + cg * 4) = s1;
        }
    }
}

// ---------------------------------------------------------------------------
// CSR build: histogram -> exclusive scan -> range-partitioned scatter
// ---------------------------------------------------------------------------
__global__ void hist_kernel(const int* __restrict__ dst, int* __restrict__ cnt, int E)
{
    int i = blockIdx.x * blockDim.x + threadIdx.x;
    int stride = gridDim.x * blockDim.x;
    for (; i < E; i += stride) atomicAdd(&cnt[dst[i]], 1);
}

__global__ void scan_block_kernel(const int* __restrict__ cnt, int* __restrict__ excl_out,
                                  int* __restrict__ part, int N)
{
    __shared__ int s[256];
    int t = threadIdx.x;
    int i = blockIdx.x * 256 + t;
    int v = (i < N) ? cnt[i] : 0;
    s[t] = v;
    __syncthreads();
    #pragma unroll
    for (int off = 1; off < 256; off <<= 1) {
        int x = (t >= off) ? s[t - off] : 0;
        __syncthreads();
        s[t] += x;
        __syncthreads();
    }
    int incl = s[t];
    if (i < N) excl_out[i] = incl - v;
    if (t == 255) part[blockIdx.x] = incl;
}

__global__ void scan_part_kernel(int* __restrict__ part, int B)
{
    __shared__ int s[512];
    int t = threadIdx.x;
    int v = (t < B) ? part[t] : 0;
    s[t] = v;
    __syncthreads();
    #pragma unroll
    for (int off = 1; off < 512; off <<= 1) {
        int x = (t >= off) ? s[t - off] : 0;
        __syncthreads();
        s[t] += x;
        __syncthreads();
    }
    int incl = s[t];
    if (t < B) part[t] = incl - v;
    if (t == B - 1) part[B] = incl;
}

__global__ void scan_final_kernel(int* __restrict__ row_ptr, const int* __restrict__ part,
                                  int* __restrict__ cursor, const int* __restrict__ cnt,
                                  float* __restrict__ dinv, int N, int B)
{
    int i = blockIdx.x * blockDim.x + threadIdx.x;
    if (i < N) {
        int rp = row_ptr[i] + part[i >> 8];
        row_ptr[i] = rp;
        cursor[i] = rp;
        dinv[i] = rsqrtf((float)(cnt[i] + 1));
    } else if (i == N) {
        row_ptr[N] = part[B];
    }
}

__global__ void scatter_kernel(const int* __restrict__ src, const int* __restrict__ dst,
                               int* __restrict__ cursor, int* __restrict__ col_idx,
                               int E, int lo, int hi)
{
    int i = blockIdx.x * blockDim.x + threadIdx.x;
    int stride = gridDim.x * blockDim.x;
    for (; i < E; i += stride) {
        int d = dst[i];
        if (d >= lo && d < hi) {
            int pos = atomicAdd(&cursor[d], 1);
            col_idx[pos] = src[i];
        }
    }
}

// ---------------------------------------------------------------------------
// GCN gather (bf16 hs): out[i] = dinv[i] * (hs[i] + sum hs[src]) + b
// 32 lanes per node, 4 bf16 (8B) per lane. Accumulate f32, write f32.
// ---------------------------------------------------------------------------
__global__ void conv_gather_bf16_kernel(const unsigned* __restrict__ hs,
                                        const int* __restrict__ row_ptr,
                                        const int* __restrict__ col_idx,
                                        const float* __restrict__ dinv,
                                        const float* __restrict__ b,
                                        float* __restrict__ out, int N)
{
    int tid = blockIdx.x * blockDim.x + threadIdx.x;
    int node = tid >> 5;
    int f4 = tid & 31;
    if (node >= N) return;
    // hs row = 64 unsigned (128 bf16); lane reads uint2 at offset f4*2
    const uint2* base = reinterpret_cast<const uint2*>(hs);
    float a0, a1, a2, a3;
    {
        uint2 v = base[(size_t)node * 32 + f4];
        a0 = bf16_lo(v.x); a1 = bf16_hi(v.x);
        a2 = bf16_lo(v.y); a3 = bf16_hi(v.y);
    }
    int e = row_ptr[node], end = row_ptr[node + 1];
    while (e < end) {
        int m = end - e;
        if (m >= 32) {
            int idx = col_idx[e + f4];
            #pragma unroll 8
            for (int j = 0; j < 32; ++j) {
                int s = __shfl(idx, j, 32);
                uint2 v = base[(size_t)s * 32 + f4];
                a0 += bf16_lo(v.x); a1 += bf16_hi(v.x);
                a2 += bf16_lo(v.y); a3 += bf16_hi(v.y);
            }
            e += 32;
        } else {
            int idx = (f4 < m) ? col_idx[e + f4] : 0;
            for (int j = 0; j < m; ++j) {
                int s = __shfl(idx, j, 32);
                uint2 v = base[(size_t)s * 32 + f4];
                a0 += bf16_lo(v.x); a1 += bf16_hi(v.x);
                a2 += bf16_lo(v.y); a3 += bf16_hi(v.y);
            }
            e = end;
        }
    }
    float di = dinv[node];
    float4 b4 = reinterpret_cast<const float4*>(b)[f4];
    float4 o;
    o.x = fmaf(di, a0, b4.x);
    o.y = fmaf(di, a1, b4.y);
    o.z = fmaf(di, a2, b4.z);
    o.w = fmaf(di, a3, b4.w);
    reinterpret_cast<float4*>(out)[(size_t)node * 32 + f4] = o;
}

// ---------------------------------------------------------------------------
// Final: out[n,0:2] = y[n] @ W_o2 + b_o2. One wave per node.
// ---------------------------------------------------------------------------
__global__ void out_kernel(const float* __restrict__ y, const float* __restrict__ W,
                           const float* __restrict__ b, float* __restrict__ out, int N)
{
    int tid = blockIdx.x * blockDim.x + threadIdx.x;
    int lane = tid & 63;
    int node = tid >> 6;
    if (node >= N) return;
    const float* r = y + (size_t)node * HID;
    float v0 = r[lane], v1 = r[lane + 64];
    float p0 = v0 * W[lane * 2 + 0] + v1 * W[(lane + 64) * 2 + 0];
    float p1 = v0 * W[lane * 2 + 1] + v1 * W[(lane + 64) * 2 + 1];
    #pragma unroll
    for (int off = 32; off; off >>= 1) {
        p0 += __shfl_down(p0, off);
        p1 += __shfl_down(p1, off);
    }
    if (lane == 0) {
        out[(size_t)node * 2 + 0] = p0 + b[0];
        out[(size_t)node * 2 + 1] = p1 + b[1];
    }
}

extern "C" void kernel_launch(void* const* d_in, const int* in_sizes, int n_in,
                              void* d_out, int out_size, void* d_ws, size_t ws_size,
                              hipStream_t stream)
{
    const float* des   = (const float*)d_in[0];
    const float* tweet = (const float*)d_in[1];
    const float* num   = (const float*)d_in[2];
    const float* cat   = (const float*)d_in[3];
    const int*   eidx  = (const int*)d_in[4];
    const float* W_des = (const float*)d_in[5];  const float* b_des = (const float*)d_in[6];
    const float* W_tw  = (const float*)d_in[7];  const float* b_tw  = (const float*)d_in[8];
    const float* W_num = (const float*)d_in[9];  const float* b_num = (const float*)d_in[10];
    const float* W_cat = (const float*)d_in[11]; const float* b_cat = (const float*)d_in[12];
    const float* W_in  = (const float*)d_in[13]; const float* b_in  = (const float*)d_in[14];
    const float* W_g1  = (const float*)d_in[15]; const float* b_g1  = (const float*)d_in[16];
    const float* W_g2  = (const float*)d_in[17]; const float* b_g2  = (const float*)d_in[18];
    const float* W_o1  = (const float*)d_in[19]; const float* b_o1  = (const float*)d_in[20];
    const float* W_o2  = (const float*)d_in[21]; const float* b_o2  = (const float*)d_in[22];
    float* out = (float*)d_out;

    const int N = in_sizes[0] / 768;
    const int E = in_sizes[4] / 2;
    const int* src = eidx;
    const int* dst = eidx + E;

    // workspace layout
    char* ws = (char*)d_ws;
    const size_t szF = (size_t)N * HID * sizeof(float);
    float* F0 = (float*)ws;                    ws += szF;
    float* F1 = (float*)ws;                    ws += szF;
    float* F2 = (float*)ws;                    ws += szF;
    int* cnt      = (int*)ws;                  ws += ((size_t)N * 4 + 255) & ~255ULL;
    int* row_ptr  = (int*)ws;                  ws += (((size_t)N + 1) * 4 + 255) & ~255ULL;
    int* cursor   = (int*)ws;                  ws += ((size_t)N * 4 + 255) & ~255ULL;
    int* part     = (int*)ws;                  ws += 4096;
    float* dinv   = (float*)ws;                ws += ((size_t)N * 4 + 255) & ~255ULL;
    int* col_idx  = (int*)ws;                  ws += (size_t)E * 4;

    const int B = (N + 255) / 256;  // scan blocks (<= 512)

    // ---- CSR build ----
    hipMemsetAsync(cnt, 0, (size_t)N * sizeof(int), stream);
    hist_kernel<<<1024, 256, 0, stream>>>(dst, cnt, E);
    scan_block_kernel<<<B, 256, 0, stream>>>(cnt, row_ptr, part, N);
    scan_part_kernel<<<1, 512, 0, stream>>>(part, B);
    scan_final_kernel<<<(N + 256) / 256 + 1, 256, 0, stream>>>(row_ptr, part, cursor, cnt, dinv, N, B);
    {
        const int NPART = 4;
        int step = (N + NPART - 1) / NPART;
        for (int p = 0; p < NPART; ++p) {
            int lo = p * step;
            int hi = (lo + step < N) ? lo + step : N;
            scatter_kernel<<<1024, 256, 0, stream>>>(src, dst, cursor, col_idx, E, lo, hi);
        }
    }

    // ---- encoder -> F0 ----
    {
        dim3 grid((N + ENC_BN - 1) / ENC_BN, 2);
        enc_gemm_kernel<<<grid, 512, 0, stream>>>(des, tweet, W_des, b_des, W_tw, b_tw, F0, N);
        enc_nc_kernel<<<((size_t)N * 64 + 255) / 256, 256, 0, stream>>>(num, cat, W_num, b_num, W_cat, b_cat, F0, N);
    }

    int ggrid = (N + 127) / 128;
    int cgrid = (int)(((size_t)N * 32 + 255) / 256);

    // ---- x1 = lrelu(x0 @ W_in + b_in) -> F1 (f32) ----
    gemm128_kernel<true, true, false, false><<<ggrid, 512, 0, stream>>>(F0, W_in, b_in, nullptr, F1, N);

    // ---- conv1: hs1 = (x1 @ W_g1) * dinv -> F2 (bf16) ; c1 -> F0 (f32) ----
    gemm128_kernel<false, false, true, true><<<ggrid, 512, 0, stream>>>(F1, W_g1, nullptr, dinv, F2, N);
    conv_gather_bf16_kernel<<<cgrid, 256, 0, stream>>>((const unsigned*)F2, row_ptr, col_idx, dinv, b_g1, F0, N);

    // ---- conv2: hs2 = (c1 @ W_g2) * dinv -> F1 (bf16) ; c2 -> F2 (f32) ----
    gemm128_kernel<false, false, true, true><<<ggrid, 512, 0, stream>>>(F0, W_g2, nullptr, dinv, F1, N);
    conv_gather_bf16_kernel<<<cgrid, 256, 0, stream>>>((const unsigned*)F1, row_ptr, col_idx, dinv, b_g2, F2, N);

    // ---- y = lrelu(c2 @ W_o1 + b_o1) -> F0 (f32) ----
    gemm128_kernel<true, true, false, false><<<ggrid, 512, 0, stream>>>(F2, W_o1, b_o1, nullptr, F0, N);

    // ---- out = y @ W_o2 + b_o2 ----
    out_kernel<<<((size_t)N * 64 + 255) / 256, 256, 0, stream>>>(F0, W_o2, b_o2, out, N);
}